// Round 3
// baseline (1435.836 us; speedup 1.0000x reference)
//
#include <hip/hip_runtime.h>

typedef unsigned short u16;
typedef unsigned int   u32;
typedef __attribute__((ext_vector_type(4))) float f32x4;
typedef __attribute__((ext_vector_type(8))) short bf16x8;

#define NG 64
#define BSH 7          // 128 nodes per bucket
#define BCAP 5120      // LDS staging capacity (edges); Poisson(4096) max ~4450, 8-sigma margin
#define PAD 16         // ints per counter (one 64B line) to kill same-line atomic serialization
#define PCH 16         // pool chunks per graph

__device__ __forceinline__ u16 f2bf(float f){
  u32 u = __float_as_uint(f);
  u += 0x7fffu + ((u >> 16) & 1u);   // RNE
  return (u16)(u >> 16);
}
__device__ __forceinline__ float bflo(u32 p){ return __uint_as_float(p << 16); }
__device__ __forceinline__ float bfhi(u32 p){ return __uint_as_float(p & 0xffff0000u); }

// ---------------- K1: bucket histogram (LDS pre-aggregated) ----------------
__global__ void bhist_kernel(const int* __restrict__ ei, int* __restrict__ bhist,
                             int E, int NBK){
  __shared__ int h[1024];
  int t = threadIdx.x;
  for (int b = t; b < 1024; b += 256) h[b] = 0;
  __syncthreads();
  for (int e = blockIdx.x * 256 + t; e < E; e += gridDim.x * 256)
    atomicAdd(&h[ei[E + e] >> BSH], 1);
  __syncthreads();
  for (int b = t; b < NBK; b += 256){
    int v = h[b];
    if (v) atomicAdd(&bhist[b * PAD], v);
  }
}

// ---------------- K2: scan bucket counts -> bases/cursors; rowptr[N]=E ----------------
__global__ void bscan_kernel(const int* __restrict__ bhist, int* __restrict__ bbase,
                             int* __restrict__ gcur, int* __restrict__ rowptr,
                             int NBK, int E, int N){
  __shared__ int sh[256];
  int t = threadIdx.x;
  int base = t * 4;
  int v[4]; int s = 0;
  #pragma unroll
  for (int j = 0; j < 4; ++j){
    int idx = base + j;
    v[j] = (idx < NBK) ? bhist[idx * PAD] : 0;
    s += v[j];
  }
  sh[t] = s; __syncthreads();
  for (int off = 1; off < 256; off <<= 1){
    int x = sh[t]; int y = (t >= off) ? sh[t - off] : 0;
    __syncthreads(); sh[t] = x + y; __syncthreads();
  }
  int run = sh[t] - s;
  #pragma unroll
  for (int j = 0; j < 4; ++j){
    int idx = base + j;
    if (idx <= NBK){ bbase[idx * PAD] = run; gcur[idx * PAD] = run; }
    run += v[j];
  }
  if (t == 0) rowptr[N] = E;
}

// ---------------- K3: bin edges into bucket-contiguous mid[] = (src, dst) ----------------
__global__ void bin_kernel(const int* __restrict__ ei, int* __restrict__ gcur,
                           int2* __restrict__ mid, int E, int NBK){
  __shared__ int hist[1024];
  __shared__ int base[1024];
  int t = threadIdx.x;
  int e0 = blockIdx.x * 8192;
  int mysrc[32], mydst[32];
  for (int b = t; b < 1024; b += 256) hist[b] = 0;
  __syncthreads();
  #pragma unroll
  for (int i = 0; i < 32; ++i){
    int e = e0 + i * 256 + t;
    int d = -1, sv = 0;
    if (e < E){ d = ei[E + e]; sv = ei[e]; atomicAdd(&hist[d >> BSH], 1); }
    mydst[i] = d; mysrc[i] = sv;
  }
  __syncthreads();
  for (int b = t; b < NBK; b += 256){
    int hh = hist[b];
    if (hh) base[b] = atomicAdd(&gcur[b * PAD], hh);
  }
  __syncthreads();
  #pragma unroll
  for (int i = 0; i < 32; ++i){
    int d = mydst[i];
    if (d >= 0){
      int p = atomicAdd(&base[d >> BSH], 1);
      mid[p] = make_int2(mysrc[i], d);
    }
  }
}

// ---------------- K4a: per-bucket node degrees -> rowptr, dinv ----------------
__global__ void nodestat_kernel(const int2* __restrict__ mid, const int* __restrict__ bbase,
                                int* __restrict__ rowptr, float* __restrict__ dinv, int N){
  __shared__ int hist[128];
  __shared__ int sh[128];
  int b = blockIdx.x, t = threadIdx.x;
  int e0 = bbase[b * PAD], e1 = bbase[(b + 1) * PAD];
  if (t < 128) hist[t] = 0;
  __syncthreads();
  for (int i = e0 + t; i < e1; i += 256) atomicAdd(&hist[mid[i].y & 127], 1);
  __syncthreads();
  int val = (t < 128) ? hist[t] : 0;
  if (t < 128) sh[t] = val;
  __syncthreads();
  for (int off = 1; off < 128; off <<= 1){
    int x = 0;
    if (t < 128){ x = sh[t]; if (t >= off) x += sh[t - off]; }
    __syncthreads();
    if (t < 128) sh[t] = x;
    __syncthreads();
  }
  if (t < 128){
    int n = b * 128 + t;
    if (n < N){
      rowptr[n] = e0 + sh[t] - val;          // exclusive prefix within bucket
      dinv[n] = rsqrtf((float)val + 1.0f);
    }
  }
}

// ---------------- K4b: per-bucket LDS scatter -> final (src, w) coalesced ----------------
__global__ __launch_bounds__(256)
void scatter_kernel(const int2* __restrict__ mid, const int* __restrict__ bbase,
                    const int* __restrict__ rowptr, const float* __restrict__ dinv,
                    int2* __restrict__ fin, int N){
  __shared__ int cur[128];
  __shared__ int2 stg[BCAP];
  int b = blockIdx.x, t = threadIdx.x;
  int e0 = bbase[b * PAD], e1 = bbase[(b + 1) * PAD];
  int sz = e1 - e0;
  if (t < 128){
    int n = b * 128 + t;
    cur[t] = ((n < N) ? rowptr[n] : e1) - e0;
  }
  __syncthreads();
  if (sz <= BCAP){
    for (int i = e0 + t; i < e1; i += 256){
      int2 m = mid[i];
      float w = dinv[m.x];
      int p = atomicAdd(&cur[m.y & 127], 1);
      stg[p] = make_int2(m.x, __float_as_int(w));
    }
    __syncthreads();
    for (int j = t; j < sz; j += 256) fin[e0 + j] = stg[j];
  } else {
    // statistically unreachable overflow fallback: direct (uncoalesced) scatter
    for (int i = e0 + t; i < e1; i += 256){
      int2 m = mid[i];
      float w = dinv[m.x];
      int p = atomicAdd(&cur[m.y & 127], 1);
      fin[e0 + p] = make_int2(m.x, __float_as_int(w));
    }
  }
}

// ---------------- weight convert + transpose to bf16 [n][k] ----------------
__global__ void wcvt_kernel(const float* __restrict__ W1, const float* __restrict__ W2,
                            u16* __restrict__ W1T, u16* __restrict__ W2T){
  int i = blockIdx.x * 256 + threadIdx.x;
  if (i < 512 * 128){ int k = i >> 7, n = i & 127; W1T[(size_t)n * 512 + k] = f2bf(W1[i]); }
  if (i < 128 * 128){ int k = i >> 7, n = i & 127; W2T[(size_t)n * 128 + k] = f2bf(W2[i]); }
}

// ---------------- MFMA GEMM: [N,K] @ [K,128] -> bf16 [N,128] (no bias) ----------------
template<int A_BF16>
__global__ __launch_bounds__(256, 3)
void gemm_kernel(const void* __restrict__ Ap, const u16* __restrict__ BT,
                 u16* __restrict__ C, int N, int K)
{
  constexpr int LDA = 40;
  __shared__ __align__(16) u16 As[128 * LDA];
  __shared__ __align__(16) u16 Bs[128 * LDA];
  const int t = threadIdx.x;
  const int wave = t >> 6, lane = t & 63;
  const int q = lane >> 4, r = lane & 15;
  const int row0 = blockIdx.x * 128;
  f32x4 zero = {0.f, 0.f, 0.f, 0.f};
  f32x4 acc[2][8];
  #pragma unroll
  for (int i = 0; i < 2; ++i)
    #pragma unroll
    for (int j = 0; j < 8; ++j) acc[i][j] = zero;

  for (int k0 = 0; k0 < K; k0 += 32){
    {
      int rr = t >> 2, cc = (t & 3) * 8;
      #pragma unroll
      for (int it = 0; it < 2; ++it){
        int n = rr + it * 64;
        uint4 v = *(const uint4*)(BT + (size_t)n * K + k0 + cc);
        *(uint4*)(&Bs[n * LDA + cc]) = v;
      }
    }
    if (A_BF16){
      const u16* A = (const u16*)Ap;
      int rr = t >> 2, cc = (t & 3) * 8;
      #pragma unroll
      for (int it = 0; it < 2; ++it){
        int rl = rr + it * 64, row = row0 + rl;
        uint4 v = make_uint4(0u, 0u, 0u, 0u);
        if (row < N) v = *(const uint4*)(A + (size_t)row * K + k0 + cc);
        *(uint4*)(&As[rl * LDA + cc]) = v;
      }
    } else {
      const float* A = (const float*)Ap;
      int rr = t >> 3, cc = (t & 7) * 4;
      #pragma unroll
      for (int it = 0; it < 4; ++it){
        int rl = rr + it * 32, row = row0 + rl;
        float4 v = make_float4(0.f, 0.f, 0.f, 0.f);
        if (row < N) v = *(const float4*)(A + (size_t)row * K + k0 + cc);
        uint2 p;
        p.x = (u32)f2bf(v.x) | ((u32)f2bf(v.y) << 16);
        p.y = (u32)f2bf(v.z) | ((u32)f2bf(v.w) << 16);
        *(uint2*)(&As[rl * LDA + cc]) = p;
      }
    }
    __syncthreads();
    bf16x8 af[2], bfr[8];
    #pragma unroll
    for (int rt = 0; rt < 2; ++rt)
      af[rt] = *(const bf16x8*)(&As[(wave * 32 + rt * 16 + r) * LDA + q * 8]);
    #pragma unroll
    for (int ct = 0; ct < 8; ++ct)
      bfr[ct] = *(const bf16x8*)(&Bs[(ct * 16 + r) * LDA + q * 8]);
    #pragma unroll
    for (int rt = 0; rt < 2; ++rt)
      #pragma unroll
      for (int ct = 0; ct < 8; ++ct)
        acc[rt][ct] = __builtin_amdgcn_mfma_f32_16x16x32_bf16(af[rt], bfr[ct], acc[rt][ct], 0, 0, 0);
    __syncthreads();
  }
  #pragma unroll
  for (int rt = 0; rt < 2; ++rt)
    #pragma unroll
    for (int reg = 0; reg < 4; ++reg){
      int row = row0 + wave * 32 + rt * 16 + q * 4 + reg;
      if (row < N)
        #pragma unroll
        for (int ct = 0; ct < 8; ++ct)
          C[(size_t)row * 128 + ct * 16 + r] = f2bf(acc[rt][ct][reg]);
    }
}

// ---------------- edge aggregation + self-loop + bias + relu (one wave/node) ----------------
// Paired-edge gathers: lanes 0-31 fetch the row of even edges, lanes 32-63 the
// row of odd edges, 8B (dwordx2) per lane. Same bytes as before but half the
// VMEM instructions and 16 edges in flight per wave (2x MLP). Cross-half
// __shfl_xor(32) merges the two partial sums; the epilogue/store uses the
// permuted element index k = 2*(lane&31)+(lane>>5) so the wave store still
// covers the full 256B row in one coalesced instruction. Tail edges padded
// with weight 0 (src clamped to row 0) so the inner loop is branch-free.
__global__ __launch_bounds__(256)
void agg_kernel(const u16* __restrict__ h, const int2* __restrict__ edges,
                const int* __restrict__ rowptr, const float* __restrict__ dinv,
                const float* __restrict__ bias, u16* __restrict__ out, int N)
{
  int node = __builtin_amdgcn_readfirstlane((int)((blockIdx.x * 256 + threadIdx.x) >> 6));
  if (node >= N) return;
  const int lane = threadIdx.x & 63;
  const int hl   = lane & 31;          // position within half-wave
  const int odd  = lane >> 5;          // 0: even-indexed edges, 1: odd-indexed
  const int k    = 2 * hl + odd;       // u32 element of the row this lane owns for I/O
  const u32* __restrict__ hp = (const u32*)h;      // row = 64 u32
  int beg = rowptr[node], end = rowptr[node + 1];

  // independent early loads
  u32 hs = hp[(size_t)node * 64 + k];
  float dv = dinv[node];
  float b0 = bias[2 * k], b1v = bias[2 * k + 1];

  // per-lane accumulators for u32 elements {2*hl, 2*hl+1} (4 features)
  float ax = 0.f, ay = 0.f, az = 0.f, aw = 0.f;
  int2 pf[16];
  #pragma unroll
  for (int i = 0; i < 16; ++i){
    int idx = beg + i;
    pf[i] = (idx < end) ? edges[idx] : make_int2(0, 0);
  }
  for (int base = beg; base < end; base += 16){
    int2 cur[16];
    #pragma unroll
    for (int i = 0; i < 16; ++i) cur[i] = pf[i];
    // prefetch next 16 edges (wave-uniform, overlaps row gathers below)
    #pragma unroll
    for (int i = 0; i < 16; ++i){
      int idx = base + 16 + i;
      pf[i] = (idx < end) ? edges[idx] : make_int2(0, 0);
    }
    // issue 8 paired row gathers (each covers 2 edges x 256B)
    uint2 v[8];
    #pragma unroll
    for (int p = 0; p < 8; ++p){
      int src = odd ? cur[2 * p + 1].x : cur[2 * p].x;
      v[p] = *(const uint2*)(hp + (size_t)src * 64 + 2 * hl);
    }
    #pragma unroll
    for (int p = 0; p < 8; ++p){
      float w = __int_as_float(odd ? cur[2 * p + 1].y : cur[2 * p].y);
      ax = fmaf(w, bflo(v[p].x), ax);
      ay = fmaf(w, bfhi(v[p].x), ay);
      az = fmaf(w, bflo(v[p].y), az);
      aw = fmaf(w, bfhi(v[p].y), aw);
    }
  }
  // merge even-edge and odd-edge halves (both halves end with full sums)
  ax += __shfl_xor(ax, 32);
  ay += __shfl_xor(ay, 32);
  az += __shfl_xor(az, 32);
  aw += __shfl_xor(aw, 32);
  // select the element this lane stores: odd=0 -> elem 2*hl, odd=1 -> elem 2*hl+1
  float s_lo = odd ? az : ax;
  float s_hi = odd ? aw : ay;
  float dv2 = dv * dv;
  s_lo = fmaf(dv, s_lo, fmaf(dv2, bflo(hs), b0));
  s_hi = fmaf(dv, s_hi, fmaf(dv2, bfhi(hs), b1v));
  s_lo = fmaxf(s_lo, 0.f); s_hi = fmaxf(s_hi, 0.f);
  u32 pk = (u32)f2bf(s_lo) | ((u32)f2bf(s_hi) << 16);
  __builtin_nontemporal_store(pk, (u32*)out + (size_t)node * 64 + k);
}

// ---------------- per-graph max pool (1 wave/block, u32 loads, x4 row unroll) ----------------
__global__ __launch_bounds__(64)
void pool_kernel(const u16* __restrict__ h, const int* __restrict__ batch,
                 float* __restrict__ g, int N)
{
  int graph = blockIdx.x >> 4, chunk = blockIdx.x & (PCH - 1);
  int t = threadIdx.x;                      // u32 element (features 2t, 2t+1)
  int lo = 0, hi = N;
  while (lo < hi){ int mid = (lo + hi) >> 1; if (batch[mid] < graph) lo = mid + 1; else hi = mid; }
  int s = lo;
  hi = N;
  while (lo < hi){ int mid = (lo + hi) >> 1; if (batch[mid] < graph + 1) lo = mid + 1; else hi = mid; }
  int epos = lo;
  int len = epos - s;
  if (len <= 0) return;
  int per = (len + PCH - 1) / PCH;
  int a = s + chunk * per;
  int b = a + per; if (b > epos) b = epos;
  if (a >= b) return;
  const u32* __restrict__ hp = (const u32*)h;   // row = 64 u32
  float m0 = 0.f, m1 = 0.f;
  int n = a;
  for (; n + 4 <= b; n += 4){
    u32 v0 = hp[(size_t)(n + 0) * 64 + t];
    u32 v1 = hp[(size_t)(n + 1) * 64 + t];
    u32 v2 = hp[(size_t)(n + 2) * 64 + t];
    u32 v3 = hp[(size_t)(n + 3) * 64 + t];
    m0 = fmaxf(fmaxf(fmaxf(m0, bflo(v0)), fmaxf(bflo(v1), bflo(v2))), bflo(v3));
    m1 = fmaxf(fmaxf(fmaxf(m1, bfhi(v0)), fmaxf(bfhi(v1), bfhi(v2))), bfhi(v3));
  }
  for (; n < b; ++n){
    u32 v = hp[(size_t)n * 64 + t];
    m0 = fmaxf(m0, bflo(v));
    m1 = fmaxf(m1, bfhi(v));
  }
  // post-ReLU values are >= 0, g is memset to 0 -> int compare == float compare
  atomicMax((int*)&g[graph * 128 + 2 * t + 0], __float_as_int(m0));
  atomicMax((int*)&g[graph * 128 + 2 * t + 1], __float_as_int(m1));
}

// ---------------- head ----------------
__global__ void head_kernel(const float* __restrict__ g, const float* __restrict__ Wc,
                            const float* __restrict__ bc, float* __restrict__ out)
{
  int gg = threadIdx.x;
  if (gg >= NG) return;
  float l0 = bc[0], l1 = bc[1];
  for (int f = 0; f < 128; ++f){
    float v = g[gg * 128 + f];
    l0 = fmaf(v, Wc[f * 2 + 0], l0);
    l1 = fmaf(v, Wc[f * 2 + 1], l1);
  }
  float m = fmaxf(l0, l1);
  float lse = m + logf(__expf(l0 - m) + __expf(l1 - m));
  out[gg * 2 + 0] = l0 - lse;
  out[gg * 2 + 1] = l1 - lse;
}

extern "C" void kernel_launch(void* const* d_in, const int* in_sizes, int n_in,
                              void* d_out, int out_size, void* d_ws, size_t ws_size,
                              hipStream_t stream)
{
  const float* x   = (const float*)d_in[0];
  const int*   ei  = (const int*)  d_in[1];
  const int*  batch= (const int*)  d_in[2];
  const float* W1  = (const float*)d_in[3];
  const float* b1  = (const float*)d_in[4];
  const float* W2  = (const float*)d_in[5];
  const float* b2  = (const float*)d_in[6];
  const float* Wc  = (const float*)d_in[7];
  const float* bc  = (const float*)d_in[8];
  float* out = (float*)d_out;
  (void)n_in; (void)out_size; (void)ws_size;

  const int N = in_sizes[0] / 512;
  const int E = in_sizes[1] / 2;
  const int NBK = (N + 127) >> 7;

  char* w = (char*)d_ws;
  size_t o = 0;
  auto take = [&](size_t bytes)->char* {
    char* p = w + o; o = (o + bytes + 511) & ~(size_t)511; return p;
  };
  size_t hbytes = (size_t)N * 128 * 2;
  size_t mbytes = (size_t)E * 8;
  int*   bhist  = (int*)  take((size_t)(NBK + 2) * PAD * 4);
  int*   bbase  = (int*)  take((size_t)(NBK + 2) * PAD * 4);
  int*   gcur   = (int*)  take((size_t)(NBK + 2) * PAD * 4);
  int*   rowptr = (int*)  take((size_t)(N + 1) * 4);
  float* dinv   = (float*)take((size_t)N * 4);
  int2*  fin    = (int2*) take(mbytes);
  u16*   W1T    = (u16*)  take((size_t)512 * 128 * 2);
  u16*   W2T    = (u16*)  take((size_t)128 * 128 * 2);
  u16*   hA     = (u16*)  take(hbytes > mbytes ? hbytes : mbytes);
  u16*   hB     = (u16*)  take(hbytes);
  float* gpool  = (float*)take((size_t)NG * 128 * 4);
  int2*  mid    = (int2*)hA;   // mid dead before gemm1 writes hA

  hipMemsetAsync(bhist, 0, (size_t)(NBK + 2) * PAD * 4, stream);
  hipMemsetAsync(gpool, 0, (size_t)NG * 128 * 4, stream);

  bhist_kernel<<<256, 256, 0, stream>>>(ei, bhist, E, NBK);
  bscan_kernel<<<1, 256, 0, stream>>>(bhist, bbase, gcur, rowptr, NBK, E, N);
  bin_kernel<<<(E + 8191) / 8192, 256, 0, stream>>>(ei, gcur, mid, E, NBK);
  nodestat_kernel<<<NBK, 256, 0, stream>>>(mid, bbase, rowptr, dinv, N);
  scatter_kernel<<<NBK, 256, 0, stream>>>(mid, bbase, rowptr, dinv, fin, N);
  wcvt_kernel<<<256, 256, 0, stream>>>(W1, W2, W1T, W2T);

  const int GB = (N + 127) / 128;
  gemm_kernel<0><<<GB, 256, 0, stream>>>((const void*)x,  W1T, hA, N, 512);
  agg_kernel<<<(N * 64 + 255) / 256, 256, 0, stream>>>(hA, fin, rowptr, dinv, b1, hB, N);
  gemm_kernel<1><<<GB, 256, 0, stream>>>((const void*)hB, W2T, hA, N, 128);
  agg_kernel<<<(N * 64 + 255) / 256, 256, 0, stream>>>(hA, fin, rowptr, dinv, b2, hB, N);
  pool_kernel<<<NG * PCH, 64, 0, stream>>>(hB, batch, gpool, N);
  head_kernel<<<1, 64, 0, stream>>>(gpool, Wc, bc, out);
}

// Round 4
// 1055.049 us; speedup vs baseline: 1.3609x; 1.3609x over previous
//
#include <hip/hip_runtime.h>

typedef unsigned short u16;
typedef unsigned int   u32;
typedef __attribute__((ext_vector_type(4))) float f32x4;
typedef __attribute__((ext_vector_type(8))) short bf16x8;

#define NG 64
#define BSH 7          // 128 nodes per bucket
#define BCAP 5120      // LDS staging capacity (edges); Poisson(4096) max ~4450, 8-sigma margin
#define PAD 16         // ints per counter (one 64B line) to kill same-line atomic serialization
#define PCH 16         // pool chunks per graph

__device__ __forceinline__ u16 f2bf(float f){
  u32 u = __float_as_uint(f);
  u += 0x7fffu + ((u >> 16) & 1u);   // RNE
  return (u16)(u >> 16);
}
__device__ __forceinline__ float bflo(u32 p){ return __uint_as_float(p << 16); }
__device__ __forceinline__ float bfhi(u32 p){ return __uint_as_float(p & 0xffff0000u); }

// ---------------- K1: bucket histogram (LDS pre-aggregated) ----------------
__global__ void bhist_kernel(const int* __restrict__ ei, int* __restrict__ bhist,
                             int E, int NBK){
  __shared__ int h[1024];
  int t = threadIdx.x;
  for (int b = t; b < 1024; b += 256) h[b] = 0;
  __syncthreads();
  for (int e = blockIdx.x * 256 + t; e < E; e += gridDim.x * 256)
    atomicAdd(&h[ei[E + e] >> BSH], 1);
  __syncthreads();
  for (int b = t; b < NBK; b += 256){
    int v = h[b];
    if (v) atomicAdd(&bhist[b * PAD], v);
  }
}

// ---------------- K2: scan bucket counts -> bases/cursors; rowptr[N]=E ----------------
__global__ void bscan_kernel(const int* __restrict__ bhist, int* __restrict__ bbase,
                             int* __restrict__ gcur, int* __restrict__ rowptr,
                             int NBK, int E, int N){
  __shared__ int sh[256];
  int t = threadIdx.x;
  int base = t * 4;
  int v[4]; int s = 0;
  #pragma unroll
  for (int j = 0; j < 4; ++j){
    int idx = base + j;
    v[j] = (idx < NBK) ? bhist[idx * PAD] : 0;
    s += v[j];
  }
  sh[t] = s; __syncthreads();
  for (int off = 1; off < 256; off <<= 1){
    int x = sh[t]; int y = (t >= off) ? sh[t - off] : 0;
    __syncthreads(); sh[t] = x + y; __syncthreads();
  }
  int run = sh[t] - s;
  #pragma unroll
  for (int j = 0; j < 4; ++j){
    int idx = base + j;
    if (idx <= NBK){ bbase[idx * PAD] = run; gcur[idx * PAD] = run; }
    run += v[j];
  }
  if (t == 0) rowptr[N] = E;
}

// ---------------- K3: bin edges into bucket-contiguous mid[] = (src, dst) ----------------
__global__ void bin_kernel(const int* __restrict__ ei, int* __restrict__ gcur,
                           int2* __restrict__ mid, int E, int NBK){
  __shared__ int hist[1024];
  __shared__ int base[1024];
  int t = threadIdx.x;
  int e0 = blockIdx.x * 8192;
  int mysrc[32], mydst[32];
  for (int b = t; b < 1024; b += 256) hist[b] = 0;
  __syncthreads();
  #pragma unroll
  for (int i = 0; i < 32; ++i){
    int e = e0 + i * 256 + t;
    int d = -1, sv = 0;
    if (e < E){ d = ei[E + e]; sv = ei[e]; atomicAdd(&hist[d >> BSH], 1); }
    mydst[i] = d; mysrc[i] = sv;
  }
  __syncthreads();
  for (int b = t; b < NBK; b += 256){
    int hh = hist[b];
    if (hh) base[b] = atomicAdd(&gcur[b * PAD], hh);
  }
  __syncthreads();
  #pragma unroll
  for (int i = 0; i < 32; ++i){
    int d = mydst[i];
    if (d >= 0){
      int p = atomicAdd(&base[d >> BSH], 1);
      mid[p] = make_int2(mysrc[i], d);
    }
  }
}

// ---------------- K4a: per-bucket node degrees -> rowptr, dinv ----------------
__global__ void nodestat_kernel(const int2* __restrict__ mid, const int* __restrict__ bbase,
                                int* __restrict__ rowptr, float* __restrict__ dinv, int N){
  __shared__ int hist[128];
  __shared__ int sh[128];
  int b = blockIdx.x, t = threadIdx.x;
  int e0 = bbase[b * PAD], e1 = bbase[(b + 1) * PAD];
  if (t < 128) hist[t] = 0;
  __syncthreads();
  for (int i = e0 + t; i < e1; i += 256) atomicAdd(&hist[mid[i].y & 127], 1);
  __syncthreads();
  int val = (t < 128) ? hist[t] : 0;
  if (t < 128) sh[t] = val;
  __syncthreads();
  for (int off = 1; off < 128; off <<= 1){
    int x = 0;
    if (t < 128){ x = sh[t]; if (t >= off) x += sh[t - off]; }
    __syncthreads();
    if (t < 128) sh[t] = x;
    __syncthreads();
  }
  if (t < 128){
    int n = b * 128 + t;
    if (n < N){
      rowptr[n] = e0 + sh[t] - val;          // exclusive prefix within bucket
      dinv[n] = rsqrtf((float)val + 1.0f);
    }
  }
}

// ---------------- K4b: per-bucket LDS scatter -> final (src, w) coalesced ----------------
__global__ __launch_bounds__(256)
void scatter_kernel(const int2* __restrict__ mid, const int* __restrict__ bbase,
                    const int* __restrict__ rowptr, const float* __restrict__ dinv,
                    int2* __restrict__ fin, int N){
  __shared__ int cur[128];
  __shared__ int2 stg[BCAP];
  int b = blockIdx.x, t = threadIdx.x;
  int e0 = bbase[b * PAD], e1 = bbase[(b + 1) * PAD];
  int sz = e1 - e0;
  if (t < 128){
    int n = b * 128 + t;
    cur[t] = ((n < N) ? rowptr[n] : e1) - e0;
  }
  __syncthreads();
  if (sz <= BCAP){
    for (int i = e0 + t; i < e1; i += 256){
      int2 m = mid[i];
      float w = dinv[m.x];
      int p = atomicAdd(&cur[m.y & 127], 1);
      stg[p] = make_int2(m.x, __float_as_int(w));
    }
    __syncthreads();
    for (int j = t; j < sz; j += 256) fin[e0 + j] = stg[j];
  } else {
    // statistically unreachable overflow fallback: direct (uncoalesced) scatter
    for (int i = e0 + t; i < e1; i += 256){
      int2 m = mid[i];
      float w = dinv[m.x];
      int p = atomicAdd(&cur[m.y & 127], 1);
      fin[e0 + p] = make_int2(m.x, __float_as_int(w));
    }
  }
}

// ---------------- weight convert + transpose to bf16 [n][k] ----------------
__global__ void wcvt_kernel(const float* __restrict__ W1, const float* __restrict__ W2,
                            u16* __restrict__ W1T, u16* __restrict__ W2T){
  int i = blockIdx.x * 256 + threadIdx.x;
  if (i < 512 * 128){ int k = i >> 7, n = i & 127; W1T[(size_t)n * 512 + k] = f2bf(W1[i]); }
  if (i < 128 * 128){ int k = i >> 7, n = i & 127; W2T[(size_t)n * 128 + k] = f2bf(W2[i]); }
}

// ---------------- MFMA GEMM: [N,K] @ [K,128] -> bf16 [N,128] (no bias) ----------------
template<int A_BF16>
__global__ __launch_bounds__(256, 3)
void gemm_kernel(const void* __restrict__ Ap, const u16* __restrict__ BT,
                 u16* __restrict__ C, int N, int K)
{
  constexpr int LDA = 40;
  __shared__ __align__(16) u16 As[128 * LDA];
  __shared__ __align__(16) u16 Bs[128 * LDA];
  const int t = threadIdx.x;
  const int wave = t >> 6, lane = t & 63;
  const int q = lane >> 4, r = lane & 15;
  const int row0 = blockIdx.x * 128;
  f32x4 zero = {0.f, 0.f, 0.f, 0.f};
  f32x4 acc[2][8];
  #pragma unroll
  for (int i = 0; i < 2; ++i)
    #pragma unroll
    for (int j = 0; j < 8; ++j) acc[i][j] = zero;

  for (int k0 = 0; k0 < K; k0 += 32){
    {
      int rr = t >> 2, cc = (t & 3) * 8;
      #pragma unroll
      for (int it = 0; it < 2; ++it){
        int n = rr + it * 64;
        uint4 v = *(const uint4*)(BT + (size_t)n * K + k0 + cc);
        *(uint4*)(&Bs[n * LDA + cc]) = v;
      }
    }
    if (A_BF16){
      const u16* A = (const u16*)Ap;
      int rr = t >> 2, cc = (t & 3) * 8;
      #pragma unroll
      for (int it = 0; it < 2; ++it){
        int rl = rr + it * 64, row = row0 + rl;
        uint4 v = make_uint4(0u, 0u, 0u, 0u);
        if (row < N) v = *(const uint4*)(A + (size_t)row * K + k0 + cc);
        *(uint4*)(&As[rl * LDA + cc]) = v;
      }
    } else {
      const float* A = (const float*)Ap;
      int rr = t >> 3, cc = (t & 7) * 4;
      #pragma unroll
      for (int it = 0; it < 4; ++it){
        int rl = rr + it * 32, row = row0 + rl;
        float4 v = make_float4(0.f, 0.f, 0.f, 0.f);
        if (row < N) v = *(const float4*)(A + (size_t)row * K + k0 + cc);
        uint2 p;
        p.x = (u32)f2bf(v.x) | ((u32)f2bf(v.y) << 16);
        p.y = (u32)f2bf(v.z) | ((u32)f2bf(v.w) << 16);
        *(uint2*)(&As[rl * LDA + cc]) = p;
      }
    }
    __syncthreads();
    bf16x8 af[2], bfr[8];
    #pragma unroll
    for (int rt = 0; rt < 2; ++rt)
      af[rt] = *(const bf16x8*)(&As[(wave * 32 + rt * 16 + r) * LDA + q * 8]);
    #pragma unroll
    for (int ct = 0; ct < 8; ++ct)
      bfr[ct] = *(const bf16x8*)(&Bs[(ct * 16 + r) * LDA + q * 8]);
    #pragma unroll
    for (int rt = 0; rt < 2; ++rt)
      #pragma unroll
      for (int ct = 0; ct < 8; ++ct)
        acc[rt][ct] = __builtin_amdgcn_mfma_f32_16x16x32_bf16(af[rt], bfr[ct], acc[rt][ct], 0, 0, 0);
    __syncthreads();
  }
  #pragma unroll
  for (int rt = 0; rt < 2; ++rt)
    #pragma unroll
    for (int reg = 0; reg < 4; ++reg){
      int row = row0 + wave * 32 + rt * 16 + q * 4 + reg;
      if (row < N)
        #pragma unroll
        for (int ct = 0; ct < 8; ++ct)
          C[(size_t)row * 128 + ct * 16 + r] = f2bf(acc[rt][ct][reg]);
    }
}

// ---------------- edge aggregation + self-loop + bias + relu (one wave/node) ----------------
// Paired-edge gathers at pipeline depth 8 (the parent kernel's exact register
// footprint: pf[8]+cur[8] wave-uniform state, 8 VGPRs of gather payload).
// Lanes 0-31 fetch rows of even edges, lanes 32-63 odd edges, dwordx2/lane:
// per iteration 8 edges via 4 paired gathers (parent: 8 edges via 8 gathers).
// Depth 16 spilled to scratch (1.66 GB WRITE_SIZE/dispatch, 553 us — round-3
// post-mortem); depth 8 must not spill. Cross-half __shfl_xor(32) merges the
// halves; epilogue/store uses permuted element k = 2*(lane&31)+(lane>>5) so
// the row store stays one coalesced wave instruction. Tail edges padded with
// weight 0 (src clamped to row 0), inner loop branch-free.
__global__ __launch_bounds__(256)
void agg_kernel(const u16* __restrict__ h, const int2* __restrict__ edges,
                const int* __restrict__ rowptr, const float* __restrict__ dinv,
                const float* __restrict__ bias, u16* __restrict__ out, int N)
{
  int node = __builtin_amdgcn_readfirstlane((int)((blockIdx.x * 256 + threadIdx.x) >> 6));
  if (node >= N) return;
  const int lane = threadIdx.x & 63;
  const int hl   = lane & 31;          // position within half-wave
  const int odd  = lane >> 5;          // 0: even-indexed edges, 1: odd-indexed
  const int k    = 2 * hl + odd;       // u32 element of the row this lane owns for I/O
  const u32* __restrict__ hp = (const u32*)h;      // row = 64 u32
  int beg = rowptr[node], end = rowptr[node + 1];

  // independent early loads
  u32 hs = hp[(size_t)node * 64 + k];
  float dv = dinv[node];
  float b0 = bias[2 * k], b1v = bias[2 * k + 1];

  // per-lane accumulators for u32 elements {2*hl, 2*hl+1} (4 features)
  float ax = 0.f, ay = 0.f, az = 0.f, aw = 0.f;
  int2 pf[8];
  #pragma unroll
  for (int i = 0; i < 8; ++i){
    int idx = beg + i;
    pf[i] = (idx < end) ? edges[idx] : make_int2(0, 0);
  }
  for (int base = beg; base < end; base += 8){
    int2 cur[8];
    #pragma unroll
    for (int i = 0; i < 8; ++i) cur[i] = pf[i];
    // prefetch next 8 edges (wave-uniform, overlaps row gathers below)
    #pragma unroll
    for (int i = 0; i < 8; ++i){
      int idx = base + 8 + i;
      pf[i] = (idx < end) ? edges[idx] : make_int2(0, 0);
    }
    // issue 4 paired row gathers (each covers 2 edges x 256B)
    uint2 v[4];
    #pragma unroll
    for (int p = 0; p < 4; ++p){
      int src = odd ? cur[2 * p + 1].x : cur[2 * p].x;
      v[p] = *(const uint2*)(hp + (size_t)src * 64 + 2 * hl);
    }
    #pragma unroll
    for (int p = 0; p < 4; ++p){
      float w = __int_as_float(odd ? cur[2 * p + 1].y : cur[2 * p].y);
      ax = fmaf(w, bflo(v[p].x), ax);
      ay = fmaf(w, bfhi(v[p].x), ay);
      az = fmaf(w, bflo(v[p].y), az);
      aw = fmaf(w, bfhi(v[p].y), aw);
    }
  }
  // merge even-edge and odd-edge halves (both halves end with full sums)
  ax += __shfl_xor(ax, 32);
  ay += __shfl_xor(ay, 32);
  az += __shfl_xor(az, 32);
  aw += __shfl_xor(aw, 32);
  // select the element this lane stores: odd=0 -> elem 2*hl, odd=1 -> elem 2*hl+1
  float s_lo = odd ? az : ax;
  float s_hi = odd ? aw : ay;
  float dv2 = dv * dv;
  s_lo = fmaf(dv, s_lo, fmaf(dv2, bflo(hs), b0));
  s_hi = fmaf(dv, s_hi, fmaf(dv2, bfhi(hs), b1v));
  s_lo = fmaxf(s_lo, 0.f); s_hi = fmaxf(s_hi, 0.f);
  u32 pk = (u32)f2bf(s_lo) | ((u32)f2bf(s_hi) << 16);
  __builtin_nontemporal_store(pk, (u32*)out + (size_t)node * 64 + k);
}

// ---------------- per-graph max pool (1 wave/block, u32 loads, x4 row unroll) ----------------
__global__ __launch_bounds__(64)
void pool_kernel(const u16* __restrict__ h, const int* __restrict__ batch,
                 float* __restrict__ g, int N)
{
  int graph = blockIdx.x >> 4, chunk = blockIdx.x & (PCH - 1);
  int t = threadIdx.x;                      // u32 element (features 2t, 2t+1)
  int lo = 0, hi = N;
  while (lo < hi){ int mid = (lo + hi) >> 1; if (batch[mid] < graph) lo = mid + 1; else hi = mid; }
  int s = lo;
  hi = N;
  while (lo < hi){ int mid = (lo + hi) >> 1; if (batch[mid] < graph + 1) lo = mid + 1; else hi = mid; }
  int epos = lo;
  int len = epos - s;
  if (len <= 0) return;
  int per = (len + PCH - 1) / PCH;
  int a = s + chunk * per;
  int b = a + per; if (b > epos) b = epos;
  if (a >= b) return;
  const u32* __restrict__ hp = (const u32*)h;   // row = 64 u32
  float m0 = 0.f, m1 = 0.f;
  int n = a;
  for (; n + 4 <= b; n += 4){
    u32 v0 = hp[(size_t)(n + 0) * 64 + t];
    u32 v1 = hp[(size_t)(n + 1) * 64 + t];
    u32 v2 = hp[(size_t)(n + 2) * 64 + t];
    u32 v3 = hp[(size_t)(n + 3) * 64 + t];
    m0 = fmaxf(fmaxf(fmaxf(m0, bflo(v0)), fmaxf(bflo(v1), bflo(v2))), bflo(v3));
    m1 = fmaxf(fmaxf(fmaxf(m1, bfhi(v0)), fmaxf(bfhi(v1), bfhi(v2))), bfhi(v3));
  }
  for (; n < b; ++n){
    u32 v = hp[(size_t)n * 64 + t];
    m0 = fmaxf(m0, bflo(v));
    m1 = fmaxf(m1, bfhi(v));
  }
  // post-ReLU values are >= 0, g is memset to 0 -> int compare == float compare
  atomicMax((int*)&g[graph * 128 + 2 * t + 0], __float_as_int(m0));
  atomicMax((int*)&g[graph * 128 + 2 * t + 1], __float_as_int(m1));
}

// ---------------- head ----------------
__global__ void head_kernel(const float* __restrict__ g, const float* __restrict__ Wc,
                            const float* __restrict__ bc, float* __restrict__ out)
{
  int gg = threadIdx.x;
  if (gg >= NG) return;
  float l0 = bc[0], l1 = bc[1];
  for (int f = 0; f < 128; ++f){
    float v = g[gg * 128 + f];
    l0 = fmaf(v, Wc[f * 2 + 0], l0);
    l1 = fmaf(v, Wc[f * 2 + 1], l1);
  }
  float m = fmaxf(l0, l1);
  float lse = m + logf(__expf(l0 - m) + __expf(l1 - m));
  out[gg * 2 + 0] = l0 - lse;
  out[gg * 2 + 1] = l1 - lse;
}

extern "C" void kernel_launch(void* const* d_in, const int* in_sizes, int n_in,
                              void* d_out, int out_size, void* d_ws, size_t ws_size,
                              hipStream_t stream)
{
  const float* x   = (const float*)d_in[0];
  const int*   ei  = (const int*)  d_in[1];
  const int*  batch= (const int*)  d_in[2];
  const float* W1  = (const float*)d_in[3];
  const float* b1  = (const float*)d_in[4];
  const float* W2  = (const float*)d_in[5];
  const float* b2  = (const float*)d_in[6];
  const float* Wc  = (const float*)d_in[7];
  const float* bc  = (const float*)d_in[8];
  float* out = (float*)d_out;
  (void)n_in; (void)out_size; (void)ws_size;

  const int N = in_sizes[0] / 512;
  const int E = in_sizes[1] / 2;
  const int NBK = (N + 127) >> 7;

  char* w = (char*)d_ws;
  size_t o = 0;
  auto take = [&](size_t bytes)->char* {
    char* p = w + o; o = (o + bytes + 511) & ~(size_t)511; return p;
  };
  size_t hbytes = (size_t)N * 128 * 2;
  size_t mbytes = (size_t)E * 8;
  int*   bhist  = (int*)  take((size_t)(NBK + 2) * PAD * 4);
  int*   bbase  = (int*)  take((size_t)(NBK + 2) * PAD * 4);
  int*   gcur   = (int*)  take((size_t)(NBK + 2) * PAD * 4);
  int*   rowptr = (int*)  take((size_t)(N + 1) * 4);
  float* dinv   = (float*)take((size_t)N * 4);
  int2*  fin    = (int2*) take(mbytes);
  u16*   W1T    = (u16*)  take((size_t)512 * 128 * 2);
  u16*   W2T    = (u16*)  take((size_t)128 * 128 * 2);
  u16*   hA     = (u16*)  take(hbytes > mbytes ? hbytes : mbytes);
  u16*   hB     = (u16*)  take(hbytes);
  float* gpool  = (float*)take((size_t)NG * 128 * 4);
  int2*  mid    = (int2*)hA;   // mid dead before gemm1 writes hA

  hipMemsetAsync(bhist, 0, (size_t)(NBK + 2) * PAD * 4, stream);
  hipMemsetAsync(gpool, 0, (size_t)NG * 128 * 4, stream);

  bhist_kernel<<<256, 256, 0, stream>>>(ei, bhist, E, NBK);
  bscan_kernel<<<1, 256, 0, stream>>>(bhist, bbase, gcur, rowptr, NBK, E, N);
  bin_kernel<<<(E + 8191) / 8192, 256, 0, stream>>>(ei, gcur, mid, E, NBK);
  nodestat_kernel<<<NBK, 256, 0, stream>>>(mid, bbase, rowptr, dinv, N);
  scatter_kernel<<<NBK, 256, 0, stream>>>(mid, bbase, rowptr, dinv, fin, N);
  wcvt_kernel<<<256, 256, 0, stream>>>(W1, W2, W1T, W2T);

  const int GB = (N + 127) / 128;
  gemm_kernel<0><<<GB, 256, 0, stream>>>((const void*)x,  W1T, hA, N, 512);
  agg_kernel<<<(N * 64 + 255) / 256, 256, 0, stream>>>(hA, fin, rowptr, dinv, b1, hB, N);
  gemm_kernel<1><<<GB, 256, 0, stream>>>((const void*)hB, W2T, hA, N, 128);
  agg_kernel<<<(N * 64 + 255) / 256, 256, 0, stream>>>(hA, fin, rowptr, dinv, b2, hB, N);
  pool_kernel<<<NG * PCH, 64, 0, stream>>>(hB, batch, gpool, N);
  head_kernel<<<1, 64, 0, stream>>>(gpool, Wc, bc, out);
}

// Round 6
// 720.552 us; speedup vs baseline: 1.9927x; 1.4642x over previous
//
#include <hip/hip_runtime.h>

typedef unsigned short u16;
typedef unsigned int   u32;
typedef __attribute__((ext_vector_type(4))) float f32x4;
typedef __attribute__((ext_vector_type(8))) short bf16x8;

#define NG 64
#define BSH 7          // 128 nodes per bucket
#define BCAP 5120      // LDS staging capacity (edges); Poisson(4096) max ~4450, 8-sigma margin
#define PAD 16         // ints per counter (one 64B line) to kill same-line atomic serialization
#define PCH 16         // pool chunks per graph

__device__ __forceinline__ u16 f2bf(float f){
  u32 u = __float_as_uint(f);
  u += 0x7fffu + ((u >> 16) & 1u);   // RNE
  return (u16)(u >> 16);
}
__device__ __forceinline__ float bflo(u32 p){ return __uint_as_float(p << 16); }
__device__ __forceinline__ float bfhi(u32 p){ return __uint_as_float(p & 0xffff0000u); }

// ---------------- K1: bucket histogram (LDS pre-aggregated) ----------------
__global__ void bhist_kernel(const int* __restrict__ ei, int* __restrict__ bhist,
                             int E, int NBK){
  __shared__ int h[1024];
  int t = threadIdx.x;
  for (int b = t; b < 1024; b += 256) h[b] = 0;
  __syncthreads();
  for (int e = blockIdx.x * 256 + t; e < E; e += gridDim.x * 256)
    atomicAdd(&h[ei[E + e] >> BSH], 1);
  __syncthreads();
  for (int b = t; b < NBK; b += 256){
    int v = h[b];
    if (v) atomicAdd(&bhist[b * PAD], v);
  }
}

// ---------------- K2: scan bucket counts -> bases/cursors; rowptr[N]=E ----------------
__global__ void bscan_kernel(const int* __restrict__ bhist, int* __restrict__ bbase,
                             int* __restrict__ gcur, int* __restrict__ rowptr,
                             int NBK, int E, int N){
  __shared__ int sh[256];
  int t = threadIdx.x;
  int base = t * 4;
  int v[4]; int s = 0;
  #pragma unroll
  for (int j = 0; j < 4; ++j){
    int idx = base + j;
    v[j] = (idx < NBK) ? bhist[idx * PAD] : 0;
    s += v[j];
  }
  sh[t] = s; __syncthreads();
  for (int off = 1; off < 256; off <<= 1){
    int x = sh[t]; int y = (t >= off) ? sh[t - off] : 0;
    __syncthreads(); sh[t] = x + y; __syncthreads();
  }
  int run = sh[t] - s;
  #pragma unroll
  for (int j = 0; j < 4; ++j){
    int idx = base + j;
    if (idx <= NBK){ bbase[idx * PAD] = run; gcur[idx * PAD] = run; }
    run += v[j];
  }
  if (t == 0) rowptr[N] = E;
}

// ---------------- K3: bin edges into bucket-contiguous mid[] = (src, dst) ----------------
__global__ void bin_kernel(const int* __restrict__ ei, int* __restrict__ gcur,
                           int2* __restrict__ mid, int E, int NBK){
  __shared__ int hist[1024];
  __shared__ int base[1024];
  int t = threadIdx.x;
  int e0 = blockIdx.x * 8192;
  int mysrc[32], mydst[32];
  for (int b = t; b < 1024; b += 256) hist[b] = 0;
  __syncthreads();
  #pragma unroll
  for (int i = 0; i < 32; ++i){
    int e = e0 + i * 256 + t;
    int d = -1, sv = 0;
    if (e < E){ d = ei[E + e]; sv = ei[e]; atomicAdd(&hist[d >> BSH], 1); }
    mydst[i] = d; mysrc[i] = sv;
  }
  __syncthreads();
  for (int b = t; b < NBK; b += 256){
    int hh = hist[b];
    if (hh) base[b] = atomicAdd(&gcur[b * PAD], hh);
  }
  __syncthreads();
  #pragma unroll
  for (int i = 0; i < 32; ++i){
    int d = mydst[i];
    if (d >= 0){
      int p = atomicAdd(&base[d >> BSH], 1);
      mid[p] = make_int2(mysrc[i], d);
    }
  }
}

// ---------------- K4a: per-bucket node degrees -> rowptr, dinv ----------------
__global__ void nodestat_kernel(const int2* __restrict__ mid, const int* __restrict__ bbase,
                                int* __restrict__ rowptr, float* __restrict__ dinv, int N){
  __shared__ int hist[128];
  __shared__ int sh[128];
  int b = blockIdx.x, t = threadIdx.x;
  int e0 = bbase[b * PAD], e1 = bbase[(b + 1) * PAD];
  if (t < 128) hist[t] = 0;
  __syncthreads();
  for (int i = e0 + t; i < e1; i += 256) atomicAdd(&hist[mid[i].y & 127], 1);
  __syncthreads();
  int val = (t < 128) ? hist[t] : 0;
  if (t < 128) sh[t] = val;
  __syncthreads();
  for (int off = 1; off < 128; off <<= 1){
    int x = 0;
    if (t < 128){ x = sh[t]; if (t >= off) x += sh[t - off]; }
    __syncthreads();
    if (t < 128) sh[t] = x;
    __syncthreads();
  }
  if (t < 128){
    int n = b * 128 + t;
    if (n < N){
      rowptr[n] = e0 + sh[t] - val;          // exclusive prefix within bucket
      dinv[n] = rsqrtf((float)val + 1.0f);
    }
  }
}

// ---------------- K4b: per-bucket LDS scatter -> final (src, w) coalesced ----------------
__global__ __launch_bounds__(256)
void scatter_kernel(const int2* __restrict__ mid, const int* __restrict__ bbase,
                    const int* __restrict__ rowptr, const float* __restrict__ dinv,
                    int2* __restrict__ fin, int N){
  __shared__ int cur[128];
  __shared__ int2 stg[BCAP];
  int b = blockIdx.x, t = threadIdx.x;
  int e0 = bbase[b * PAD], e1 = bbase[(b + 1) * PAD];
  int sz = e1 - e0;
  if (t < 128){
    int n = b * 128 + t;
    cur[t] = ((n < N) ? rowptr[n] : e1) - e0;
  }
  __syncthreads();
  if (sz <= BCAP){
    for (int i = e0 + t; i < e1; i += 256){
      int2 m = mid[i];
      float w = dinv[m.x];
      int p = atomicAdd(&cur[m.y & 127], 1);
      stg[p] = make_int2(m.x, __float_as_int(w));
    }
    __syncthreads();
    for (int j = t; j < sz; j += 256) fin[e0 + j] = stg[j];
  } else {
    // statistically unreachable overflow fallback: direct (uncoalesced) scatter
    for (int i = e0 + t; i < e1; i += 256){
      int2 m = mid[i];
      float w = dinv[m.x];
      int p = atomicAdd(&cur[m.y & 127], 1);
      fin[e0 + p] = make_int2(m.x, __float_as_int(w));
    }
  }
}

// ---------------- weight convert + transpose to bf16 [n][k] ----------------
__global__ void wcvt_kernel(const float* __restrict__ W1, const float* __restrict__ W2,
                            u16* __restrict__ W1T, u16* __restrict__ W2T){
  int i = blockIdx.x * 256 + threadIdx.x;
  if (i < 512 * 128){ int k = i >> 7, n = i & 127; W1T[(size_t)n * 512 + k] = f2bf(W1[i]); }
  if (i < 128 * 128){ int k = i >> 7, n = i & 127; W2T[(size_t)n * 128 + k] = f2bf(W2[i]); }
}

// ---------------- MFMA GEMM: [N,K] @ [K,128] -> bf16 [N,128] (no bias) ----------------
template<int A_BF16>
__global__ __launch_bounds__(256, 3)
void gemm_kernel(const void* __restrict__ Ap, const u16* __restrict__ BT,
                 u16* __restrict__ C, int N, int K)
{
  constexpr int LDA = 40;
  __shared__ __align__(16) u16 As[128 * LDA];
  __shared__ __align__(16) u16 Bs[128 * LDA];
  const int t = threadIdx.x;
  const int wave = t >> 6, lane = t & 63;
  const int q = lane >> 4, r = lane & 15;
  const int row0 = blockIdx.x * 128;
  f32x4 zero = {0.f, 0.f, 0.f, 0.f};
  f32x4 acc[2][8];
  #pragma unroll
  for (int i = 0; i < 2; ++i)
    #pragma unroll
    for (int j = 0; j < 8; ++j) acc[i][j] = zero;

  for (int k0 = 0; k0 < K; k0 += 32){
    {
      int rr = t >> 2, cc = (t & 3) * 8;
      #pragma unroll
      for (int it = 0; it < 2; ++it){
        int n = rr + it * 64;
        uint4 v = *(const uint4*)(BT + (size_t)n * K + k0 + cc);
        *(uint4*)(&Bs[n * LDA + cc]) = v;
      }
    }
    if (A_BF16){
      const u16* A = (const u16*)Ap;
      int rr = t >> 2, cc = (t & 3) * 8;
      #pragma unroll
      for (int it = 0; it < 2; ++it){
        int rl = rr + it * 64, row = row0 + rl;
        uint4 v = make_uint4(0u, 0u, 0u, 0u);
        if (row < N) v = *(const uint4*)(A + (size_t)row * K + k0 + cc);
        *(uint4*)(&As[rl * LDA + cc]) = v;
      }
    } else {
      const float* A = (const float*)Ap;
      int rr = t >> 3, cc = (t & 7) * 4;
      #pragma unroll
      for (int it = 0; it < 4; ++it){
        int rl = rr + it * 32, row = row0 + rl;
        float4 v = make_float4(0.f, 0.f, 0.f, 0.f);
        if (row < N) v = *(const float4*)(A + (size_t)row * K + k0 + cc);
        uint2 p;
        p.x = (u32)f2bf(v.x) | ((u32)f2bf(v.y) << 16);
        p.y = (u32)f2bf(v.z) | ((u32)f2bf(v.w) << 16);
        *(uint2*)(&As[rl * LDA + cc]) = p;
      }
    }
    __syncthreads();
    bf16x8 af[2], bfr[8];
    #pragma unroll
    for (int rt = 0; rt < 2; ++rt)
      af[rt] = *(const bf16x8*)(&As[(wave * 32 + rt * 16 + r) * LDA + q * 8]);
    #pragma unroll
    for (int ct = 0; ct < 8; ++ct)
      bfr[ct] = *(const bf16x8*)(&Bs[(ct * 16 + r) * LDA + q * 8]);
    #pragma unroll
    for (int rt = 0; rt < 2; ++rt)
      #pragma unroll
      for (int ct = 0; ct < 8; ++ct)
        acc[rt][ct] = __builtin_amdgcn_mfma_f32_16x16x32_bf16(af[rt], bfr[ct], acc[rt][ct], 0, 0, 0);
    __syncthreads();
  }
  #pragma unroll
  for (int rt = 0; rt < 2; ++rt)
    #pragma unroll
    for (int reg = 0; reg < 4; ++reg){
      int row = row0 + wave * 32 + rt * 16 + q * 4 + reg;
      if (row < N)
        #pragma unroll
        for (int ct = 0; ct < 8; ++ct)
          C[(size_t)row * 128 + ct * 16 + r] = f2bf(acc[rt][ct][reg]);
    }
}

// ---------------- edge aggregation + self-loop + bias + relu (one wave/node) ----------------
// Paired-edge dwordx2 gathers, depth-8 pipeline in NAMED SCALARS ONLY.
// Round-4 post-mortem: pf[8]/cur[8] allocas were promoted to LDS by the
// compiler (LDS_Block_Size=16384, 1.36e8 bank conflicts, 32-way per access)
// -> 295us. Named registers cannot be promoted. edges (fin) carries a
// 16-entry zero pad past E so all pipeline loads are unguarded; stale-slot
// weights are zeroed by the per-slot (idx<end) select, stale srcs are valid
// rows (or 0 from the pad) so gathers never fault and contribute w*row = 0.
// Lanes 0-31 own even edge slots, 32-63 odd slots; __shfl_xor(32) merges;
// epilogue element k = 2*(lane&31)+(lane>>5) keeps row I/O one coalesced
// wave instruction.
__global__ __launch_bounds__(256)
void agg_kernel(const u16* __restrict__ h, const int2* __restrict__ edges,
                const int* __restrict__ rowptr, const float* __restrict__ dinv,
                const float* __restrict__ bias, u16* __restrict__ out, int N)
{
  int node = __builtin_amdgcn_readfirstlane((int)((blockIdx.x * 256 + threadIdx.x) >> 6));
  if (node >= N) return;
  const int lane = threadIdx.x & 63;
  const int hl   = lane & 31;          // position within half-wave
  const int odd  = lane >> 5;          // 0: even-indexed edge slots, 1: odd
  const int k    = 2 * hl + odd;       // u32 element of the row this lane owns for I/O
  const u32* __restrict__ hp = (const u32*)h;      // row = 64 u32
  int beg = rowptr[node], end = rowptr[node + 1];

  // independent early loads
  u32 hs = hp[(size_t)node * 64 + k];
  float dv = dinv[node];
  float b0 = bias[2 * k], b1v = bias[2 * k + 1];

  float ax = 0.f, ay = 0.f, az = 0.f, aw = 0.f;

  int2 p0 = edges[beg + 0], p1 = edges[beg + 1], p2 = edges[beg + 2], p3 = edges[beg + 3],
       p4 = edges[beg + 4], p5 = edges[beg + 5], p6 = edges[beg + 6], p7 = edges[beg + 7];
  for (int base = beg; base < end; base += 8){
    int2 c0 = p0, c1 = p1, c2 = p2, c3 = p3, c4 = p4, c5 = p5, c6 = p6, c7 = p7;
    // prefetch next 8 edge slots (wave-uniform; overlaps the gathers below)
    p0 = edges[base +  8]; p1 = edges[base +  9]; p2 = edges[base + 10]; p3 = edges[base + 11];
    p4 = edges[base + 12]; p5 = edges[base + 13]; p6 = edges[base + 14]; p7 = edges[base + 15];
    // 4 paired row gathers (each instruction covers 2 edges x 256B)
    int s0 = odd ? c1.x : c0.x;
    int s1 = odd ? c3.x : c2.x;
    int s2 = odd ? c5.x : c4.x;
    int s3 = odd ? c7.x : c6.x;
    uint2 v0 = *(const uint2*)(hp + (size_t)s0 * 64 + 2 * hl);
    uint2 v1 = *(const uint2*)(hp + (size_t)s1 * 64 + 2 * hl);
    uint2 v2 = *(const uint2*)(hp + (size_t)s2 * 64 + 2 * hl);
    uint2 v3 = *(const uint2*)(hp + (size_t)s3 * 64 + 2 * hl);
    // per-slot weight, zeroed past end (slot index = base + 2*p + odd)
    float w0 = (base + 0 + odd < end) ? __int_as_float(odd ? c1.y : c0.y) : 0.f;
    float w1 = (base + 2 + odd < end) ? __int_as_float(odd ? c3.y : c2.y) : 0.f;
    float w2 = (base + 4 + odd < end) ? __int_as_float(odd ? c5.y : c4.y) : 0.f;
    float w3 = (base + 6 + odd < end) ? __int_as_float(odd ? c7.y : c6.y) : 0.f;
    ax = fmaf(w0, bflo(v0.x), ax); ay = fmaf(w0, bfhi(v0.x), ay);
    az = fmaf(w0, bflo(v0.y), az); aw = fmaf(w0, bfhi(v0.y), aw);
    ax = fmaf(w1, bflo(v1.x), ax); ay = fmaf(w1, bfhi(v1.x), ay);
    az = fmaf(w1, bflo(v1.y), az); aw = fmaf(w1, bfhi(v1.y), aw);
    ax = fmaf(w2, bflo(v2.x), ax); ay = fmaf(w2, bfhi(v2.x), ay);
    az = fmaf(w2, bflo(v2.y), az); aw = fmaf(w2, bfhi(v2.y), aw);
    ax = fmaf(w3, bflo(v3.x), ax); ay = fmaf(w3, bfhi(v3.x), ay);
    az = fmaf(w3, bflo(v3.y), az); aw = fmaf(w3, bfhi(v3.y), aw);
  }
  // merge even-slot and odd-slot halves (both halves end with full sums)
  ax += __shfl_xor(ax, 32);
  ay += __shfl_xor(ay, 32);
  az += __shfl_xor(az, 32);
  aw += __shfl_xor(aw, 32);
  // element this lane stores: odd=0 -> elem 2*hl, odd=1 -> elem 2*hl+1
  float s_lo = odd ? az : ax;
  float s_hi = odd ? aw : ay;
  float dv2 = dv * dv;
  s_lo = fmaf(dv, s_lo, fmaf(dv2, bflo(hs), b0));
  s_hi = fmaf(dv, s_hi, fmaf(dv2, bfhi(hs), b1v));
  s_lo = fmaxf(s_lo, 0.f); s_hi = fmaxf(s_hi, 0.f);
  u32 pk = (u32)f2bf(s_lo) | ((u32)f2bf(s_hi) << 16);
  __builtin_nontemporal_store(pk, (u32*)out + (size_t)node * 64 + k);
}

// ---------------- per-graph max pool (1 wave/block, u32 loads, x4 row unroll) ----------------
__global__ __launch_bounds__(64)
void pool_kernel(const u16* __restrict__ h, const int* __restrict__ batch,
                 float* __restrict__ g, int N)
{
  int graph = blockIdx.x >> 4, chunk = blockIdx.x & (PCH - 1);
  int t = threadIdx.x;                      // u32 element (features 2t, 2t+1)
  int lo = 0, hi = N;
  while (lo < hi){ int mid = (lo + hi) >> 1; if (batch[mid] < graph) lo = mid + 1; else hi = mid; }
  int s = lo;
  hi = N;
  while (lo < hi){ int mid = (lo + hi) >> 1; if (batch[mid] < graph + 1) lo = mid + 1; else hi = mid; }
  int epos = lo;
  int len = epos - s;
  if (len <= 0) return;
  int per = (len + PCH - 1) / PCH;
  int a = s + chunk * per;
  int b = a + per; if (b > epos) b = epos;
  if (a >= b) return;
  const u32* __restrict__ hp = (const u32*)h;   // row = 64 u32
  float m0 = 0.f, m1 = 0.f;
  int n = a;
  for (; n + 4 <= b; n += 4){
    u32 v0 = hp[(size_t)(n + 0) * 64 + t];
    u32 v1 = hp[(size_t)(n + 1) * 64 + t];
    u32 v2 = hp[(size_t)(n + 2) * 64 + t];
    u32 v3 = hp[(size_t)(n + 3) * 64 + t];
    m0 = fmaxf(fmaxf(fmaxf(m0, bflo(v0)), fmaxf(bflo(v1), bflo(v2))), bflo(v3));
    m1 = fmaxf(fmaxf(fmaxf(m1, bfhi(v0)), fmaxf(bfhi(v1), bfhi(v2))), bfhi(v3));
  }
  for (; n < b; ++n){
    u32 v = hp[(size_t)n * 64 + t];
    m0 = fmaxf(m0, bflo(v));
    m1 = fmaxf(m1, bfhi(v));
  }
  // post-ReLU values are >= 0, g is memset to 0 -> int compare == float compare
  atomicMax((int*)&g[graph * 128 + 2 * t + 0], __float_as_int(m0));
  atomicMax((int*)&g[graph * 128 + 2 * t + 1], __float_as_int(m1));
}

// ---------------- head ----------------
__global__ void head_kernel(const float* __restrict__ g, const float* __restrict__ Wc,
                            const float* __restrict__ bc, float* __restrict__ out)
{
  int gg = threadIdx.x;
  if (gg >= NG) return;
  float l0 = bc[0], l1 = bc[1];
  for (int f = 0; f < 128; ++f){
    float v = g[gg * 128 + f];
    l0 = fmaf(v, Wc[f * 2 + 0], l0);
    l1 = fmaf(v, Wc[f * 2 + 1], l1);
  }
  float m = fmaxf(l0, l1);
  float lse = m + logf(__expf(l0 - m) + __expf(l1 - m));
  out[gg * 2 + 0] = l0 - lse;
  out[gg * 2 + 1] = l1 - lse;
}

extern "C" void kernel_launch(void* const* d_in, const int* in_sizes, int n_in,
                              void* d_out, int out_size, void* d_ws, size_t ws_size,
                              hipStream_t stream)
{
  const float* x   = (const float*)d_in[0];
  const int*   ei  = (const int*)  d_in[1];
  const int*  batch= (const int*)  d_in[2];
  const float* W1  = (const float*)d_in[3];
  const float* b1  = (const float*)d_in[4];
  const float* W2  = (const float*)d_in[5];
  const float* b2  = (const float*)d_in[6];
  const float* Wc  = (const float*)d_in[7];
  const float* bc  = (const float*)d_in[8];
  float* out = (float*)d_out;
  (void)n_in; (void)out_size; (void)ws_size;

  const int N = in_sizes[0] / 512;
  const int E = in_sizes[1] / 2;
  const int NBK = (N + 127) >> 7;

  char* w = (char*)d_ws;
  size_t o = 0;
  auto take = [&](size_t bytes)->char* {
    char* p = w + o; o = (o + bytes + 511) & ~(size_t)511; return p;
  };
  size_t hbytes = (size_t)N * 128 * 2;
  size_t mbytes = (size_t)E * 8;
  int*   bhist  = (int*)  take((size_t)(NBK + 2) * PAD * 4);
  int*   bbase  = (int*)  take((size_t)(NBK + 2) * PAD * 4);
  int*   gcur   = (int*)  take((size_t)(NBK + 2) * PAD * 4);
  int*   rowptr = (int*)  take((size_t)(N + 1) * 4);
  float* dinv   = (float*)take((size_t)N * 4);
  int2*  fin    = (int2*) take(mbytes + 16 * sizeof(int2));   // +16 zero pad for unguarded pipeline loads
  u16*   W1T    = (u16*)  take((size_t)512 * 128 * 2);
  u16*   W2T    = (u16*)  take((size_t)128 * 128 * 2);
  u16*   hA     = (u16*)  take(hbytes > mbytes ? hbytes : mbytes);
  u16*   hB     = (u16*)  take(hbytes);
  float* gpool  = (float*)take((size_t)NG * 128 * 4);
  int2*  mid    = (int2*)hA;   // mid dead before gemm1 writes hA

  hipMemsetAsync(bhist, 0, (size_t)(NBK + 2) * PAD * 4, stream);
  hipMemsetAsync(gpool, 0, (size_t)NG * 128 * 4, stream);
  hipMemsetAsync(fin + E, 0, 16 * sizeof(int2), stream);   // zero the pad once

  bhist_kernel<<<256, 256, 0, stream>>>(ei, bhist, E, NBK);
  bscan_kernel<<<1, 256, 0, stream>>>(bhist, bbase, gcur, rowptr, NBK, E, N);
  bin_kernel<<<(E + 8191) / 8192, 256, 0, stream>>>(ei, gcur, mid, E, NBK);
  nodestat_kernel<<<NBK, 256, 0, stream>>>(mid, bbase, rowptr, dinv, N);
  scatter_kernel<<<NBK, 256, 0, stream>>>(mid, bbase, rowptr, dinv, fin, N);
  wcvt_kernel<<<256, 256, 0, stream>>>(W1, W2, W1T, W2T);

  const int GB = (N + 127) / 128;
  gemm_kernel<0><<<GB, 256, 0, stream>>>((const void*)x,  W1T, hA, N, 512);
  agg_kernel<<<(N * 64 + 255) / 256, 256, 0, stream>>>(hA, fin, rowptr, dinv, b1, hB, N);
  gemm_kernel<1><<<GB, 256, 0, stream>>>((const void*)hB, W2T, hA, N, 128);
  agg_kernel<<<(N * 64 + 255) / 256, 256, 0, stream>>>(hA, fin, rowptr, dinv, b2, hB, N);
  pool_kernel<<<NG * PCH, 64, 0, stream>>>(hB, batch, gpool, N);
  head_kernel<<<1, 64, 0, stream>>>(gpool, Wc, bc, out);
}